// Round 5
// baseline (976.326 us; speedup 1.0000x reference)
//
#include <hip/hip_runtime.h>
#include <hip/hip_bf16.h>
#include <math.h>

#define TB 256

typedef __attribute__((ext_vector_type(8))) short bf16x8;
typedef __attribute__((ext_vector_type(4))) float f32x4;

__device__ inline float bf2f(ushort u) {
    union { uint u; float f; } c; c.u = ((uint)u) << 16; return c.f;
}
__device__ inline ushort f2bf(float f) {
    __hip_bfloat16 h = __float2bfloat16(f);
    union { __hip_bfloat16 h; ushort u; } c; c.h = h; return c.u;
}

// ---------------- weight transpose+cast: WT[n][k] = bf16(W[k][n]) ----------------

__global__ __launch_bounds__(256) void k_tcast(const float* __restrict__ W,
                                               ushort* __restrict__ WT, int K, int N) {
    int id = blockIdx.x * blockDim.x + threadIdx.x;
    if (id >= K * N) return;
    int k = id / N, nn = id % N;
    WT[(size_t)nn * K + k] = f2bf(W[id]);
}

// ---------------- degree / normalization ----------------

__global__ __launch_bounds__(256) void k_init_deg(int* deg, int* cursor, int n) {
    int i = blockIdx.x * blockDim.x + threadIdx.x;
    if (i < n) { deg[i] = 1; cursor[i] = 0; }
}

__global__ __launch_bounds__(256) void k_count_deg(const int* __restrict__ dst, int E, int* deg) {
    int i = blockIdx.x * blockDim.x + threadIdx.x;
    if (i < E) atomicAdd(&deg[dst[i]], 1);
}

__global__ __launch_bounds__(256) void k_dis(const int* __restrict__ deg, float* __restrict__ dis, int n) {
    int i = blockIdx.x * blockDim.x + threadIdx.x;
    if (i < n) dis[i] = rsqrtf((float)deg[i]);
}

// ---------------- exclusive scan of in-edge counts (deg-1), single block ----------------

__global__ __launch_bounds__(1024) void k_scan(const int* __restrict__ deg, int* __restrict__ offsets, int n) {
    __shared__ int sums[1024];
    int t = threadIdx.x;
    int C = (n + 1023) / 1024;
    int lo = t * C, hi = min(n, lo + C);
    int s = 0;
    for (int i = lo; i < hi; ++i) s += deg[i] - 1;
    sums[t] = s;
    __syncthreads();
    for (int off = 1; off < 1024; off <<= 1) {
        int v = (t >= off) ? sums[t - off] : 0;
        __syncthreads();
        sums[t] += v;
        __syncthreads();
    }
    int base = (t == 0) ? 0 : sums[t - 1];
    for (int i = lo; i < hi; ++i) { offsets[i] = base; base += deg[i] - 1; }
}

// ---------------- CSR fill (by dst), also caches dis[src] per edge ----------------

__global__ __launch_bounds__(256) void k_fill(const int* __restrict__ src, const int* __restrict__ dst, int E,
                                              const int* __restrict__ offsets, int* cursor,
                                              const float* __restrict__ dis,
                                              int* __restrict__ csr_src,
                                              float* __restrict__ csr_w) {
    int e = blockIdx.x * blockDim.x + threadIdx.x;
    if (e >= E) return;
    int d = dst[e];
    int s = src[e];
    int pos = offsets[d] + atomicAdd(&cursor[d], 1);
    csr_src[pos] = s;
    csr_w[pos]   = dis[s];
}

// ---------------- bf16 MFMA GEMM: C[M,N] = A[M,K] @ BT[N,K]^T ----------------
// BM=128, BN=64, BK=32; 4 waves (2x2); each wave 64x32 = 4x2 frags of 16x16.
// AFP32: A is fp32, converted to bf16 during staging (fuses the cast pass).

__device__ inline uint relu_pk(uint u) {
    uint lo = u & 0x0000FFFFu;
    uint hi = u & 0xFFFF0000u;
    if (u & 0x00008000u) lo = 0;
    if (u & 0x80000000u) hi = 0;
    return lo | hi;
}

template <bool AFP32, bool RELU>
__global__ __launch_bounds__(256) void k_gemm_mfma(const void* __restrict__ Av,
                                                   const ushort* __restrict__ BT,
                                                   ushort* __restrict__ C,
                                                   int M, int N, int K) {
    const int BM = 128, BN = 64, BK = 32;
    __shared__ ushort Al[BM][40];   // pad to 40 (80 B rows) to spread banks
    __shared__ ushort Bl[BN][40];

    const int t    = threadIdx.x;
    const int lane = t & 63;
    const int wid  = t >> 6;
    const int wm   = wid >> 1, wn = wid & 1;
    const int m0   = blockIdx.x * BM, n0 = blockIdx.y * BN;
    const int lr   = lane & 15;     // row/col within fragment
    const int lg   = lane >> 4;     // k-group

    f32x4 acc[4][2] = {};

    for (int k0 = 0; k0 < K; k0 += BK) {
        // stage A: 128 rows x 32 bf16; 512 chunks of 8 elems; 2 per thread
        #pragma unroll
        for (int i = 0; i < 2; ++i) {
            int c = t + i * 256;
            int row = c >> 2, q = c & 3;
            int gm = m0 + row;
            if (AFP32) {
                const float* Af = (const float*)Av;
                ushort4 o0 = {0,0,0,0}, o1 = {0,0,0,0};
                if (gm < M) {
                    const float* ap = Af + (size_t)gm * K + k0 + q * 8;
                    float4 u = *(const float4*)ap;
                    float4 w = *(const float4*)(ap + 4);
                    o0.x = f2bf(u.x); o0.y = f2bf(u.y); o0.z = f2bf(u.z); o0.w = f2bf(u.w);
                    o1.x = f2bf(w.x); o1.y = f2bf(w.y); o1.z = f2bf(w.z); o1.w = f2bf(w.w);
                }
                *(ushort4*)(&Al[row][q * 8])     = o0;
                *(ushort4*)(&Al[row][q * 8 + 4]) = o1;
            } else {
                const ushort* Ab = (const ushort*)Av;
                uint4 v = make_uint4(0, 0, 0, 0);
                if (gm < M) v = *(const uint4*)(Ab + (size_t)gm * K + k0 + q * 8);
                if (RELU) { v.x = relu_pk(v.x); v.y = relu_pk(v.y); v.z = relu_pk(v.z); v.w = relu_pk(v.w); }
                *(uint4*)(&Al[row][q * 8]) = v;
            }
        }
        // stage B: 64 rows x 32 bf16; 256 chunks; 1 per thread
        {
            int row = t >> 2, q = t & 3;
            uint4 v = *(const uint4*)(BT + (size_t)(n0 + row) * K + k0 + q * 8);
            *(uint4*)(&Bl[row][q * 8]) = v;
        }
        __syncthreads();

        bf16x8 fa[4], fb[2];
        #pragma unroll
        for (int mi = 0; mi < 4; ++mi)
            fa[mi] = *(const bf16x8*)(&Al[wm * 64 + mi * 16 + lr][lg * 8]);
        #pragma unroll
        for (int ni = 0; ni < 2; ++ni)
            fb[ni] = *(const bf16x8*)(&Bl[wn * 32 + ni * 16 + lr][lg * 8]);
        #pragma unroll
        for (int mi = 0; mi < 4; ++mi)
            #pragma unroll
            for (int ni = 0; ni < 2; ++ni)
                acc[mi][ni] = __builtin_amdgcn_mfma_f32_16x16x32_bf16(fa[mi], fb[ni], acc[mi][ni], 0, 0, 0);
        __syncthreads();
    }

    // epilogue: D row=(lg)*4+v, col=lr
    #pragma unroll
    for (int mi = 0; mi < 4; ++mi) {
        int rbase = m0 + wm * 64 + mi * 16 + lg * 4;
        #pragma unroll
        for (int v = 0; v < 4; ++v) {
            int gm = rbase + v;
            if (gm < M) {
                #pragma unroll
                for (int ni = 0; ni < 2; ++ni)
                    C[(size_t)gm * N + n0 + wn * 32 + ni * 16 + lr] = f2bf(acc[mi][ni][v]);
            }
        }
    }
}

// ---------------- gather aggregation (bf16 h), one wave per dst node, 4-deep MLP ----------------

__global__ __launch_bounds__(256) void k_agg256(const ushort* __restrict__ h,
                                                const int* __restrict__ csr,
                                                const float* __restrict__ csr_w,
                                                const int* __restrict__ off,
                                                const int* __restrict__ deg,
                                                const float* __restrict__ dis,
                                                const float* __restrict__ bias,
                                                ushort* __restrict__ out, int n) {
    int wave = (int)((blockIdx.x * (size_t)blockDim.x + threadIdx.x) >> 6);
    int lane = threadIdx.x & 63;
    if (wave >= n) return;
    const int i = wave;
    const float di = dis[i];
    const int beg = off[i], cnt = deg[i] - 1, end = beg + cnt;

    float4 bv = ((const float4*)bias)[lane];
    ushort4 hv = ((const ushort4*)(h + (size_t)i * 256))[lane];
    float sl = di * di;
    float4 a0, a1 = {0,0,0,0}, a2 = {0,0,0,0}, a3 = {0,0,0,0};
    a0.x = fmaf(bf2f(hv.x), sl, bv.x);
    a0.y = fmaf(bf2f(hv.y), sl, bv.y);
    a0.z = fmaf(bf2f(hv.z), sl, bv.z);
    a0.w = fmaf(bf2f(hv.w), sl, bv.w);

    for (int base = beg; base < end; base += 64) {
        int m = end - base; if (m > 64) m = 64;
        int   msrc = (lane < m) ? csr[base + lane] : 0;
        float mw   = (lane < m) ? csr_w[base + lane] * di : 0.f;
        int k = 0;
        for (; k + 4 <= m; k += 4) {
            int s0 = __shfl(msrc, k),     s1 = __shfl(msrc, k + 1);
            int s2 = __shfl(msrc, k + 2), s3 = __shfl(msrc, k + 3);
            float w0 = __shfl(mw, k),     w1 = __shfl(mw, k + 1);
            float w2 = __shfl(mw, k + 2), w3 = __shfl(mw, k + 3);
            ushort4 v0 = ((const ushort4*)(h + (size_t)s0 * 256))[lane];
            ushort4 v1 = ((const ushort4*)(h + (size_t)s1 * 256))[lane];
            ushort4 v2 = ((const ushort4*)(h + (size_t)s2 * 256))[lane];
            ushort4 v3 = ((const ushort4*)(h + (size_t)s3 * 256))[lane];
            a0.x = fmaf(bf2f(v0.x), w0, a0.x); a0.y = fmaf(bf2f(v0.y), w0, a0.y);
            a0.z = fmaf(bf2f(v0.z), w0, a0.z); a0.w = fmaf(bf2f(v0.w), w0, a0.w);
            a1.x = fmaf(bf2f(v1.x), w1, a1.x); a1.y = fmaf(bf2f(v1.y), w1, a1.y);
            a1.z = fmaf(bf2f(v1.z), w1, a1.z); a1.w = fmaf(bf2f(v1.w), w1, a1.w);
            a2.x = fmaf(bf2f(v2.x), w2, a2.x); a2.y = fmaf(bf2f(v2.y), w2, a2.y);
            a2.z = fmaf(bf2f(v2.z), w2, a2.z); a2.w = fmaf(bf2f(v2.w), w2, a2.w);
            a3.x = fmaf(bf2f(v3.x), w3, a3.x); a3.y = fmaf(bf2f(v3.y), w3, a3.y);
            a3.z = fmaf(bf2f(v3.z), w3, a3.z); a3.w = fmaf(bf2f(v3.w), w3, a3.w);
        }
        for (; k < m; ++k) {
            int   s0 = __shfl(msrc, k); float w0 = __shfl(mw, k);
            ushort4 v0 = ((const ushort4*)(h + (size_t)s0 * 256))[lane];
            a0.x = fmaf(bf2f(v0.x), w0, a0.x); a0.y = fmaf(bf2f(v0.y), w0, a0.y);
            a0.z = fmaf(bf2f(v0.z), w0, a0.z); a0.w = fmaf(bf2f(v0.w), w0, a0.w);
        }
    }
    ushort4 o;
    o.x = f2bf((a0.x + a1.x) + (a2.x + a3.x));
    o.y = f2bf((a0.y + a1.y) + (a2.y + a3.y));
    o.z = f2bf((a0.z + a1.z) + (a2.z + a3.z));
    o.w = f2bf((a0.w + a1.w) + (a2.w + a3.w));
    ((ushort4*)(out + (size_t)i * 256))[lane] = o;
}

// agg64 fused with log-softmax: one wave per node; lane == class
__global__ __launch_bounds__(256) void k_agg64_lsm(const ushort* __restrict__ h,
                                                   const int* __restrict__ csr,
                                                   const float* __restrict__ csr_w,
                                                   const int* __restrict__ off,
                                                   const int* __restrict__ deg,
                                                   const float* __restrict__ dis,
                                                   const float* __restrict__ bias,
                                                   float* __restrict__ out, int n) {
    int wave = (int)((blockIdx.x * (size_t)blockDim.x + threadIdx.x) >> 6);
    int lane = threadIdx.x & 63;
    if (wave >= n) return;
    const int i = wave;
    const float di = dis[i];
    const int beg = off[i], cnt = deg[i] - 1, end = beg + cnt;

    float a0 = fmaf(bf2f(h[(size_t)i * 64 + lane]), di * di, bias[lane]);
    float a1 = 0.f, a2 = 0.f, a3 = 0.f;

    for (int base = beg; base < end; base += 64) {
        int m = end - base; if (m > 64) m = 64;
        int   msrc = (lane < m) ? csr[base + lane] : 0;
        float mw   = (lane < m) ? csr_w[base + lane] * di : 0.f;
        int k = 0;
        for (; k + 4 <= m; k += 4) {
            int s0 = __shfl(msrc, k),     s1 = __shfl(msrc, k + 1);
            int s2 = __shfl(msrc, k + 2), s3 = __shfl(msrc, k + 3);
            float w0 = __shfl(mw, k),     w1 = __shfl(mw, k + 1);
            float w2 = __shfl(mw, k + 2), w3 = __shfl(mw, k + 3);
            a0 = fmaf(bf2f(h[(size_t)s0 * 64 + lane]), w0, a0);
            a1 = fmaf(bf2f(h[(size_t)s1 * 64 + lane]), w1, a1);
            a2 = fmaf(bf2f(h[(size_t)s2 * 64 + lane]), w2, a2);
            a3 = fmaf(bf2f(h[(size_t)s3 * 64 + lane]), w3, a3);
        }
        for (; k < m; ++k) {
            int s0 = __shfl(msrc, k); float w0 = __shfl(mw, k);
            a0 = fmaf(bf2f(h[(size_t)s0 * 64 + lane]), w0, a0);
        }
    }
    float v = (a0 + a1) + (a2 + a3);

    // log-softmax across the wave (64 classes, 1 per lane)
    float mx = v;
    #pragma unroll
    for (int o = 32; o > 0; o >>= 1) mx = fmaxf(mx, __shfl_xor(mx, o));
    float ex = __expf(v - mx);
    float ssum = ex;
    #pragma unroll
    for (int o = 32; o > 0; o >>= 1) ssum += __shfl_xor(ssum, o);
    out[(size_t)i * 64 + lane] = v - mx - logf(ssum);
}

// ---------------- launch ----------------

extern "C" void kernel_launch(void* const* d_in, const int* in_sizes, int n_in,
                              void* d_out, int out_size, void* d_ws, size_t ws_size,
                              hipStream_t stream) {
    const float* x  = (const float*)d_in[0];
    const int*   ei = (const int*)d_in[1];
    const float* W1 = (const float*)d_in[2];
    const float* b1 = (const float*)d_in[3];
    const float* W2 = (const float*)d_in[4];
    const float* b2 = (const float*)d_in[5];
    float* out = (float*)d_out;

    const int n = in_sizes[0] / 512;     // 100000
    const int E = in_sizes[1] / 2;       // 3200000
    const int* src = ei;
    const int* dst = ei + E;

    // workspace layout (bytes), 16B-aligned blocks
    char* ws = (char*)d_ws;
    int*    deg     = (int*)(ws + 0);               //    400,000
    int*    cursor  = (int*)(ws + 400000);          //    400,000
    float*  dis     = (float*)(ws + 800000);        //    400,000
    int*    offsets = (int*)(ws + 1200000);         //    400,000
    int*    csr_src = (int*)(ws + 1600000);         // 12,800,000 -> 14,400,000
    float*  csr_w   = (float*)(ws + 14400000);      // 12,800,000 -> 27,200,000
    ushort* W1T     = (ushort*)(ws + 27200000);     //    262,144 -> 27,462,144
    ushort* W2T     = (ushort*)(ws + 27462144);     //     32,768 -> 27,494,912
    ushort* h1      = (ushort*)(ws + 27494912);     // 51,200,000 -> 78,694,912
    ushort* out1    = (ushort*)(ws + 78694912);     // 51,200,000 -> 129,894,912
    ushort* h2      = (ushort*)(ws + 129894912);    // 12,800,000 -> 142,694,912

    // 0. weight transposes
    k_tcast<<<(512 * 256 + TB - 1) / TB, TB, 0, stream>>>(W1, W1T, 512, 256);
    k_tcast<<<(256 * 64 + TB - 1) / TB, TB, 0, stream>>>(W2, W2T, 256, 64);

    // 1. CSR build (with cached per-edge dis[src])
    k_init_deg<<<(n + TB - 1) / TB, TB, 0, stream>>>(deg, cursor, n);
    k_count_deg<<<(E + TB - 1) / TB, TB, 0, stream>>>(dst, E, deg);
    k_dis<<<(n + TB - 1) / TB, TB, 0, stream>>>(deg, dis, n);
    k_scan<<<1, 1024, 0, stream>>>(deg, offsets, n);
    k_fill<<<(E + TB - 1) / TB, TB, 0, stream>>>(src, dst, E, offsets, cursor, dis, csr_src, csr_w);

    // 2. h1 = x @ W1  (fp32 A converted in staging — no separate cast pass)
    {
        dim3 grid((n + 127) / 128, 256 / 64);
        k_gemm_mfma<true, false><<<grid, TB, 0, stream>>>(x, W1T, h1, n, 256, 512);
    }

    // 3. out1 = b1 + Â h1
    k_agg256<<<(n + 3) / 4, TB, 0, stream>>>(h1, csr_src, csr_w, offsets, deg, dis, b1, out1, n);

    // 4. h2 = relu(out1) @ W2  (relu fused into A staging)
    {
        dim3 grid((n + 127) / 128, 1);
        k_gemm_mfma<false, true><<<grid, TB, 0, stream>>>(out1, W2T, h2, n, 64, 256);
    }

    // 5. out = b2 + Â h2, log-softmax fused (one pass, final write)
    k_agg64_lsm<<<(n + 3) / 4, TB, 0, stream>>>(h2, csr_src, csr_w, offsets, deg, dis, b2, out, n);
}

// Round 6
// 966.572 us; speedup vs baseline: 1.0101x; 1.0101x over previous
//
#include <hip/hip_runtime.h>
#include <hip/hip_bf16.h>
#include <math.h>

#define TB 256

typedef __attribute__((ext_vector_type(8))) short bf16x8;
typedef __attribute__((ext_vector_type(4))) float f32x4;

__device__ inline float bf2f(ushort u) {
    union { uint u; float f; } c; c.u = ((uint)u) << 16; return c.f;
}
__device__ inline ushort f2bf(float f) {
    __hip_bfloat16 h = __float2bfloat16(f);
    union { __hip_bfloat16 h; ushort u; } c; c.h = h; return c.u;
}
__device__ inline float i2f(int i) { union { int i; float f; } c; c.i = i; return c.f; }
__device__ inline int f2i(float f) { union { float f; int i; } c; c.f = f; return c.i; }

// ---------------- weight transpose+cast: WT[n][k] = bf16(W[k][n]) ----------------

__global__ __launch_bounds__(256) void k_tcast(const float* __restrict__ W,
                                               ushort* __restrict__ WT, int K, int N) {
    int id = blockIdx.x * blockDim.x + threadIdx.x;
    if (id >= K * N) return;
    int k = id / N, nn = id % N;
    WT[(size_t)nn * K + k] = f2bf(W[id]);
}

// ---------------- degree / normalization ----------------

__global__ __launch_bounds__(256) void k_init_deg(int* deg, int n) {
    int i = blockIdx.x * blockDim.x + threadIdx.x;
    if (i < n) deg[i] = 1;
}

__global__ __launch_bounds__(256) void k_count_deg(const int* __restrict__ dst, int E, int* deg) {
    int i = blockIdx.x * blockDim.x + threadIdx.x;
    if (i < E) atomicAdd(&deg[dst[i]], 1);
}

__global__ __launch_bounds__(256) void k_dis(const int* __restrict__ deg, float* __restrict__ dis, int n) {
    int i = blockIdx.x * blockDim.x + threadIdx.x;
    if (i < n) dis[i] = rsqrtf((float)deg[i]);
}

// ---------------- exclusive scan of in-edge counts (deg-1); also cursor=offsets ----------------

__global__ __launch_bounds__(1024) void k_scan(const int* __restrict__ deg,
                                               int* __restrict__ offsets,
                                               int* __restrict__ cursor, int n) {
    __shared__ int sums[1024];
    int t = threadIdx.x;
    int C = (n + 1023) / 1024;
    int lo = t * C, hi = min(n, lo + C);
    int s = 0;
    for (int i = lo; i < hi; ++i) s += deg[i] - 1;
    sums[t] = s;
    __syncthreads();
    for (int off = 1; off < 1024; off <<= 1) {
        int v = (t >= off) ? sums[t - off] : 0;
        __syncthreads();
        sums[t] += v;
        __syncthreads();
    }
    int base = (t == 0) ? 0 : sums[t - 1];
    for (int i = lo; i < hi; ++i) {
        offsets[i] = base;
        cursor[i]  = base;
        base += deg[i] - 1;
    }
}

// ---------------- CSR fill (by dst): single packed int2 {src, dis[src]} per edge ----------------

__global__ __launch_bounds__(256) void k_fill(const int* __restrict__ src, const int* __restrict__ dst, int E,
                                              int* cursor,
                                              const float* __restrict__ dis,
                                              int2* __restrict__ csr_p) {
    int e = blockIdx.x * blockDim.x + threadIdx.x;
    if (e >= E) return;
    int d = dst[e];
    int s = src[e];
    int pos = atomicAdd(&cursor[d], 1);
    csr_p[pos] = make_int2(s, f2i(dis[s]));
}

// ---------------- bf16 MFMA GEMM: C[M,N] = A[M,K] @ BT[N,K]^T ----------------
// BM=128, BN=64, BK=32; 4 waves (2x2); each wave 64x32 = 4x2 frags of 16x16.
// AFP32: A is fp32, converted to bf16 during staging (fuses the cast pass).

__device__ inline uint relu_pk(uint u) {
    uint lo = u & 0x0000FFFFu;
    uint hi = u & 0xFFFF0000u;
    if (u & 0x00008000u) lo = 0;
    if (u & 0x80000000u) hi = 0;
    return lo | hi;
}

template <bool AFP32, bool RELU>
__global__ __launch_bounds__(256) void k_gemm_mfma(const void* __restrict__ Av,
                                                   const ushort* __restrict__ BT,
                                                   ushort* __restrict__ C,
                                                   int M, int N, int K) {
    const int BM = 128, BN = 64, BK = 32;
    __shared__ ushort Al[BM][40];   // pad to 40 (80 B rows) to spread banks
    __shared__ ushort Bl[BN][40];

    const int t    = threadIdx.x;
    const int lane = t & 63;
    const int wid  = t >> 6;
    const int wm   = wid >> 1, wn = wid & 1;
    const int m0   = blockIdx.x * BM, n0 = blockIdx.y * BN;
    const int lr   = lane & 15;
    const int lg   = lane >> 4;

    f32x4 acc[4][2] = {};

    for (int k0 = 0; k0 < K; k0 += BK) {
        #pragma unroll
        for (int i = 0; i < 2; ++i) {
            int c = t + i * 256;
            int row = c >> 2, q = c & 3;
            int gm = m0 + row;
            if (AFP32) {
                const float* Af = (const float*)Av;
                ushort4 o0 = {0,0,0,0}, o1 = {0,0,0,0};
                if (gm < M) {
                    const float* ap = Af + (size_t)gm * K + k0 + q * 8;
                    float4 u = *(const float4*)ap;
                    float4 w = *(const float4*)(ap + 4);
                    o0.x = f2bf(u.x); o0.y = f2bf(u.y); o0.z = f2bf(u.z); o0.w = f2bf(u.w);
                    o1.x = f2bf(w.x); o1.y = f2bf(w.y); o1.z = f2bf(w.z); o1.w = f2bf(w.w);
                }
                *(ushort4*)(&Al[row][q * 8])     = o0;
                *(ushort4*)(&Al[row][q * 8 + 4]) = o1;
            } else {
                const ushort* Ab = (const ushort*)Av;
                uint4 v = make_uint4(0, 0, 0, 0);
                if (gm < M) v = *(const uint4*)(Ab + (size_t)gm * K + k0 + q * 8);
                if (RELU) { v.x = relu_pk(v.x); v.y = relu_pk(v.y); v.z = relu_pk(v.z); v.w = relu_pk(v.w); }
                *(uint4*)(&Al[row][q * 8]) = v;
            }
        }
        {
            int row = t >> 2, q = t & 3;
            uint4 v = *(const uint4*)(BT + (size_t)(n0 + row) * K + k0 + q * 8);
            *(uint4*)(&Bl[row][q * 8]) = v;
        }
        __syncthreads();

        bf16x8 fa[4], fb[2];
        #pragma unroll
        for (int mi = 0; mi < 4; ++mi)
            fa[mi] = *(const bf16x8*)(&Al[wm * 64 + mi * 16 + lr][lg * 8]);
        #pragma unroll
        for (int ni = 0; ni < 2; ++ni)
            fb[ni] = *(const bf16x8*)(&Bl[wn * 32 + ni * 16 + lr][lg * 8]);
        #pragma unroll
        for (int mi = 0; mi < 4; ++mi)
            #pragma unroll
            for (int ni = 0; ni < 2; ++ni)
                acc[mi][ni] = __builtin_amdgcn_mfma_f32_16x16x32_bf16(fa[mi], fb[ni], acc[mi][ni], 0, 0, 0);
        __syncthreads();
    }

    #pragma unroll
    for (int mi = 0; mi < 4; ++mi) {
        int rbase = m0 + wm * 64 + mi * 16 + lg * 4;
        #pragma unroll
        for (int v = 0; v < 4; ++v) {
            int gm = rbase + v;
            if (gm < M) {
                #pragma unroll
                for (int ni = 0; ni < 2; ++ni)
                    C[(size_t)gm * N + n0 + wn * 32 + ni * 16 + lr] = f2bf(acc[mi][ni][v]);
            }
        }
    }
}

// ---------------- gather aggregation (bf16 h), one wave per dst node, 4-deep MLP ----------------

__global__ __launch_bounds__(256) void k_agg256(const ushort* __restrict__ h,
                                                const int2* __restrict__ csr_p,
                                                const int* __restrict__ off,
                                                const int* __restrict__ deg,
                                                const float* __restrict__ dis,
                                                const float* __restrict__ bias,
                                                ushort* __restrict__ out, int n) {
    int wave = (int)((blockIdx.x * (size_t)blockDim.x + threadIdx.x) >> 6);
    int lane = threadIdx.x & 63;
    if (wave >= n) return;
    const int i = wave;
    const float di = dis[i];
    const int beg = off[i], cnt = deg[i] - 1, end = beg + cnt;

    float4 bv = ((const float4*)bias)[lane];
    ushort4 hv = ((const ushort4*)(h + (size_t)i * 256))[lane];
    float sl = di * di;
    float4 a0, a1 = {0,0,0,0}, a2 = {0,0,0,0}, a3 = {0,0,0,0};
    a0.x = fmaf(bf2f(hv.x), sl, bv.x);
    a0.y = fmaf(bf2f(hv.y), sl, bv.y);
    a0.z = fmaf(bf2f(hv.z), sl, bv.z);
    a0.w = fmaf(bf2f(hv.w), sl, bv.w);

    for (int base = beg; base < end; base += 64) {
        int m = end - base; if (m > 64) m = 64;
        int2 p = (lane < m) ? csr_p[base + lane] : make_int2(0, 0);
        int   msrc = p.x;
        float mw   = (lane < m) ? i2f(p.y) * di : 0.f;
        int k = 0;
        for (; k + 4 <= m; k += 4) {
            int s0 = __shfl(msrc, k),     s1 = __shfl(msrc, k + 1);
            int s2 = __shfl(msrc, k + 2), s3 = __shfl(msrc, k + 3);
            float w0 = __shfl(mw, k),     w1 = __shfl(mw, k + 1);
            float w2 = __shfl(mw, k + 2), w3 = __shfl(mw, k + 3);
            ushort4 v0 = ((const ushort4*)(h + (size_t)s0 * 256))[lane];
            ushort4 v1 = ((const ushort4*)(h + (size_t)s1 * 256))[lane];
            ushort4 v2 = ((const ushort4*)(h + (size_t)s2 * 256))[lane];
            ushort4 v3 = ((const ushort4*)(h + (size_t)s3 * 256))[lane];
            a0.x = fmaf(bf2f(v0.x), w0, a0.x); a0.y = fmaf(bf2f(v0.y), w0, a0.y);
            a0.z = fmaf(bf2f(v0.z), w0, a0.z); a0.w = fmaf(bf2f(v0.w), w0, a0.w);
            a1.x = fmaf(bf2f(v1.x), w1, a1.x); a1.y = fmaf(bf2f(v1.y), w1, a1.y);
            a1.z = fmaf(bf2f(v1.z), w1, a1.z); a1.w = fmaf(bf2f(v1.w), w1, a1.w);
            a2.x = fmaf(bf2f(v2.x), w2, a2.x); a2.y = fmaf(bf2f(v2.y), w2, a2.y);
            a2.z = fmaf(bf2f(v2.z), w2, a2.z); a2.w = fmaf(bf2f(v2.w), w2, a2.w);
            a3.x = fmaf(bf2f(v3.x), w3, a3.x); a3.y = fmaf(bf2f(v3.y), w3, a3.y);
            a3.z = fmaf(bf2f(v3.z), w3, a3.z); a3.w = fmaf(bf2f(v3.w), w3, a3.w);
        }
        for (; k < m; ++k) {
            int   s0 = __shfl(msrc, k); float w0 = __shfl(mw, k);
            ushort4 v0 = ((const ushort4*)(h + (size_t)s0 * 256))[lane];
            a0.x = fmaf(bf2f(v0.x), w0, a0.x); a0.y = fmaf(bf2f(v0.y), w0, a0.y);
            a0.z = fmaf(bf2f(v0.z), w0, a0.z); a0.w = fmaf(bf2f(v0.w), w0, a0.w);
        }
    }
    ushort4 o;
    o.x = f2bf((a0.x + a1.x) + (a2.x + a3.x));
    o.y = f2bf((a0.y + a1.y) + (a2.y + a3.y));
    o.z = f2bf((a0.z + a1.z) + (a2.z + a3.z));
    o.w = f2bf((a0.w + a1.w) + (a2.w + a3.w));
    ((ushort4*)(out + (size_t)i * 256))[lane] = o;
}

// agg64 fused with log-softmax: one wave per node; lane == class
__global__ __launch_bounds__(256) void k_agg64_lsm(const ushort* __restrict__ h,
                                                   const int2* __restrict__ csr_p,
                                                   const int* __restrict__ off,
                                                   const int* __restrict__ deg,
                                                   const float* __restrict__ dis,
                                                   const float* __restrict__ bias,
                                                   float* __restrict__ out, int n) {
    int wave = (int)((blockIdx.x * (size_t)blockDim.x + threadIdx.x) >> 6);
    int lane = threadIdx.x & 63;
    if (wave >= n) return;
    const int i = wave;
    const float di = dis[i];
    const int beg = off[i], cnt = deg[i] - 1, end = beg + cnt;

    float a0 = fmaf(bf2f(h[(size_t)i * 64 + lane]), di * di, bias[lane]);
    float a1 = 0.f, a2 = 0.f, a3 = 0.f;

    for (int base = beg; base < end; base += 64) {
        int m = end - base; if (m > 64) m = 64;
        int2 p = (lane < m) ? csr_p[base + lane] : make_int2(0, 0);
        int   msrc = p.x;
        float mw   = (lane < m) ? i2f(p.y) * di : 0.f;
        int k = 0;
        for (; k + 4 <= m; k += 4) {
            int s0 = __shfl(msrc, k),     s1 = __shfl(msrc, k + 1);
            int s2 = __shfl(msrc, k + 2), s3 = __shfl(msrc, k + 3);
            float w0 = __shfl(mw, k),     w1 = __shfl(mw, k + 1);
            float w2 = __shfl(mw, k + 2), w3 = __shfl(mw, k + 3);
            a0 = fmaf(bf2f(h[(size_t)s0 * 64 + lane]), w0, a0);
            a1 = fmaf(bf2f(h[(size_t)s1 * 64 + lane]), w1, a1);
            a2 = fmaf(bf2f(h[(size_t)s2 * 64 + lane]), w2, a2);
            a3 = fmaf(bf2f(h[(size_t)s3 * 64 + lane]), w3, a3);
        }
        for (; k < m; ++k) {
            int s0 = __shfl(msrc, k); float w0 = __shfl(mw, k);
            a0 = fmaf(bf2f(h[(size_t)s0 * 64 + lane]), w0, a0);
        }
    }
    float v = (a0 + a1) + (a2 + a3);

    float mx = v;
    #pragma unroll
    for (int o = 32; o > 0; o >>= 1) mx = fmaxf(mx, __shfl_xor(mx, o));
    float ex = __expf(v - mx);
    float ssum = ex;
    #pragma unroll
    for (int o = 32; o > 0; o >>= 1) ssum += __shfl_xor(ssum, o);
    out[(size_t)i * 64 + lane] = v - mx - logf(ssum);
}

// ---------------- launch ----------------

extern "C" void kernel_launch(void* const* d_in, const int* in_sizes, int n_in,
                              void* d_out, int out_size, void* d_ws, size_t ws_size,
                              hipStream_t stream) {
    const float* x  = (const float*)d_in[0];
    const int*   ei = (const int*)d_in[1];
    const float* W1 = (const float*)d_in[2];
    const float* b1 = (const float*)d_in[3];
    const float* W2 = (const float*)d_in[4];
    const float* b2 = (const float*)d_in[5];
    float* out = (float*)d_out;

    const int n = in_sizes[0] / 512;     // 100000
    const int E = in_sizes[1] / 2;       // 3200000
    const int* src = ei;
    const int* dst = ei + E;

    // workspace layout (bytes), 16B-aligned blocks
    char* ws = (char*)d_ws;
    int*    deg     = (int*)(ws + 0);               //    400,000
    int*    cursor  = (int*)(ws + 400000);          //    400,000
    float*  dis     = (float*)(ws + 800000);        //    400,000
    int*    offsets = (int*)(ws + 1200000);         //    400,000
    int2*   csr_p   = (int2*)(ws + 1600000);        // 25,600,000 -> 27,200,000
    ushort* W1T     = (ushort*)(ws + 27200000);     //    262,144 -> 27,462,144
    ushort* W2T     = (ushort*)(ws + 27462144);     //     32,768 -> 27,494,912
    ushort* h1      = (ushort*)(ws + 27494912);     // 51,200,000 -> 78,694,912
    ushort* out1    = (ushort*)(ws + 78694912);     // 51,200,000 -> 129,894,912
    ushort* h2      = (ushort*)(ws + 129894912);    // 12,800,000 -> 142,694,912

    // 0. weight transposes
    k_tcast<<<(512 * 256 + TB - 1) / TB, TB, 0, stream>>>(W1, W1T, 512, 256);
    k_tcast<<<(256 * 64 + TB - 1) / TB, TB, 0, stream>>>(W2, W2T, 256, 64);

    // 1. CSR build (packed {src, dis[src]}; cursor pre-seeded with offsets in k_scan)
    k_init_deg<<<(n + TB - 1) / TB, TB, 0, stream>>>(deg, n);
    k_count_deg<<<(E + TB - 1) / TB, TB, 0, stream>>>(dst, E, deg);
    k_dis<<<(n + TB - 1) / TB, TB, 0, stream>>>(deg, dis, n);
    k_scan<<<1, 1024, 0, stream>>>(deg, offsets, cursor, n);
    k_fill<<<(E + TB - 1) / TB, TB, 0, stream>>>(src, dst, E, cursor, dis, csr_p);

    // 2. h1 = x @ W1  (fp32 A converted in staging — no separate cast pass)
    {
        dim3 grid((n + 127) / 128, 256 / 64);
        k_gemm_mfma<true, false><<<grid, TB, 0, stream>>>(x, W1T, h1, n, 256, 512);
    }

    // 3. out1 = b1 + Â h1
    k_agg256<<<(n + 3) / 4, TB, 0, stream>>>(h1, csr_p, offsets, deg, dis, b1, out1, n);

    // 4. h2 = relu(out1) @ W2  (relu fused into A staging)
    {
        dim3 grid((n + 127) / 128, 1);
        k_gemm_mfma<false, true><<<grid, TB, 0, stream>>>(out1, W2T, h2, n, 64, 256);
    }

    // 5. out = b2 + Â h2, log-softmax fused (one pass, final write)
    k_agg64_lsm<<<(n + 3) / 4, TB, 0, stream>>>(h2, csr_p, offsets, deg, dis, b2, out, n);
}

// Round 7
// 760.389 us; speedup vs baseline: 1.2840x; 1.2712x over previous
//
#include <hip/hip_runtime.h>
#include <hip/hip_bf16.h>
#include <math.h>

#define TB 256

typedef __attribute__((ext_vector_type(8))) short bf16x8;
typedef __attribute__((ext_vector_type(4))) float f32x4;

__device__ inline float bf2f(ushort u) {
    union { uint u; float f; } c; c.u = ((uint)u) << 16; return c.f;
}
__device__ inline ushort f2bf(float f) {
    __hip_bfloat16 h = __float2bfloat16(f);
    union { __hip_bfloat16 h; ushort u; } c; c.h = h; return c.u;
}
__device__ inline float i2f(int i) { union { int i; float f; } c; c.i = i; return c.f; }
__device__ inline int f2i(float f) { union { float f; int i; } c; c.f = f; return c.i; }

// ---------------- weight transpose+cast: WT[n][k] = bf16(W[k][n]) ----------------

__global__ __launch_bounds__(256) void k_tcast(const float* __restrict__ W,
                                               ushort* __restrict__ WT, int K, int N) {
    int id = blockIdx.x * blockDim.x + threadIdx.x;
    if (id >= K * N) return;
    int k = id / N, nn = id % N;
    WT[(size_t)nn * K + k] = f2bf(W[id]);
}

// ---------------- degree / normalization ----------------

__global__ __launch_bounds__(256) void k_init_deg(int* deg, int n) {
    int i = blockIdx.x * blockDim.x + threadIdx.x;
    if (i < n) deg[i] = 1;
}

__global__ __launch_bounds__(256) void k_count_deg(const int* __restrict__ dst, int E, int* deg) {
    int i = blockIdx.x * blockDim.x + threadIdx.x;
    if (i < E) atomicAdd(&deg[dst[i]], 1);
}

__global__ __launch_bounds__(256) void k_dis(const int* __restrict__ deg, float* __restrict__ dis, int n) {
    int i = blockIdx.x * blockDim.x + threadIdx.x;
    if (i < n) dis[i] = rsqrtf((float)deg[i]);
}

// ---------------- hierarchical exclusive scan of (deg-1), 1024 elems per block ----------------

__global__ __launch_bounds__(256) void k_scan_partial(const int* __restrict__ deg,
                                                      int* __restrict__ partials, int n) {
    __shared__ int red[256];
    int base = blockIdx.x * 1024;
    int t = threadIdx.x;
    int s = 0;
    #pragma unroll
    for (int j = 0; j < 4; ++j) {
        int i = base + t * 4 + j;
        if (i < n) s += deg[i] - 1;
    }
    red[t] = s;
    __syncthreads();
    for (int off = 128; off > 0; off >>= 1) {
        if (t < off) red[t] += red[t + off];
        __syncthreads();
    }
    if (t == 0) partials[blockIdx.x] = red[0];
}

__global__ __launch_bounds__(128) void k_scan_tops(int* __restrict__ partials, int B) {
    __shared__ int sh[128];
    int t = threadIdx.x;
    int v = (t < B) ? partials[t] : 0;
    sh[t] = v;
    __syncthreads();
    for (int off = 1; off < 128; off <<= 1) {
        int u = (t >= off) ? sh[t - off] : 0;
        __syncthreads();
        sh[t] += u;
        __syncthreads();
    }
    if (t < B) partials[t] = sh[t] - v;   // exclusive
}

__global__ __launch_bounds__(256) void k_scan_final(const int* __restrict__ deg,
                                                    const int* __restrict__ partials,
                                                    int* __restrict__ offsets,
                                                    int* __restrict__ cursor, int n) {
    __shared__ int sh[256];
    int base = blockIdx.x * 1024;
    int t = threadIdx.x;
    int c[4];
    int s = 0;
    #pragma unroll
    for (int j = 0; j < 4; ++j) {
        int i = base + t * 4 + j;
        c[j] = (i < n) ? deg[i] - 1 : 0;
        s += c[j];
    }
    sh[t] = s;
    __syncthreads();
    for (int off = 1; off < 256; off <<= 1) {
        int u = (t >= off) ? sh[t - off] : 0;
        __syncthreads();
        sh[t] += u;
        __syncthreads();
    }
    int run = partials[blockIdx.x] + sh[t] - s;   // exclusive base for this thread
    #pragma unroll
    for (int j = 0; j < 4; ++j) {
        int i = base + t * 4 + j;
        if (i < n) { offsets[i] = run; cursor[i] = run; run += c[j]; }
    }
}

// ---------------- CSR fill (by dst): single packed int2 {src, dis[src]} per edge ----------------

__global__ __launch_bounds__(256) void k_fill(const int* __restrict__ src, const int* __restrict__ dst, int E,
                                              int* cursor,
                                              const float* __restrict__ dis,
                                              int2* __restrict__ csr_p) {
    int e = blockIdx.x * blockDim.x + threadIdx.x;
    if (e >= E) return;
    int d = dst[e];
    int s = src[e];
    int pos = atomicAdd(&cursor[d], 1);
    csr_p[pos] = make_int2(s, f2i(dis[s]));
}

// ---------------- bf16 MFMA GEMM: C[M,N] = A[M,K] @ BT[N,K]^T ----------------

__device__ inline uint relu_pk(uint u) {
    uint lo = u & 0x0000FFFFu;
    uint hi = u & 0xFFFF0000u;
    if (u & 0x00008000u) lo = 0;
    if (u & 0x80000000u) hi = 0;
    return lo | hi;
}

template <bool AFP32, bool RELU>
__global__ __launch_bounds__(256) void k_gemm_mfma(const void* __restrict__ Av,
                                                   const ushort* __restrict__ BT,
                                                   ushort* __restrict__ C,
                                                   int M, int N, int K) {
    const int BM = 128, BN = 64, BK = 32;
    __shared__ ushort Al[BM][40];
    __shared__ ushort Bl[BN][40];

    const int t    = threadIdx.x;
    const int lane = t & 63;
    const int wid  = t >> 6;
    const int wm   = wid >> 1, wn = wid & 1;
    const int m0   = blockIdx.x * BM, n0 = blockIdx.y * BN;
    const int lr   = lane & 15;
    const int lg   = lane >> 4;

    f32x4 acc[4][2] = {};

    for (int k0 = 0; k0 < K; k0 += BK) {
        #pragma unroll
        for (int i = 0; i < 2; ++i) {
            int c = t + i * 256;
            int row = c >> 2, q = c & 3;
            int gm = m0 + row;
            if (AFP32) {
                const float* Af = (const float*)Av;
                ushort4 o0 = {0,0,0,0}, o1 = {0,0,0,0};
                if (gm < M) {
                    const float* ap = Af + (size_t)gm * K + k0 + q * 8;
                    float4 u = *(const float4*)ap;
                    float4 w = *(const float4*)(ap + 4);
                    o0.x = f2bf(u.x); o0.y = f2bf(u.y); o0.z = f2bf(u.z); o0.w = f2bf(u.w);
                    o1.x = f2bf(w.x); o1.y = f2bf(w.y); o1.z = f2bf(w.z); o1.w = f2bf(w.w);
                }
                *(ushort4*)(&Al[row][q * 8])     = o0;
                *(ushort4*)(&Al[row][q * 8 + 4]) = o1;
            } else {
                const ushort* Ab = (const ushort*)Av;
                uint4 v = make_uint4(0, 0, 0, 0);
                if (gm < M) v = *(const uint4*)(Ab + (size_t)gm * K + k0 + q * 8);
                if (RELU) { v.x = relu_pk(v.x); v.y = relu_pk(v.y); v.z = relu_pk(v.z); v.w = relu_pk(v.w); }
                *(uint4*)(&Al[row][q * 8]) = v;
            }
        }
        {
            int row = t >> 2, q = t & 3;
            uint4 v = *(const uint4*)(BT + (size_t)(n0 + row) * K + k0 + q * 8);
            *(uint4*)(&Bl[row][q * 8]) = v;
        }
        __syncthreads();

        bf16x8 fa[4], fb[2];
        #pragma unroll
        for (int mi = 0; mi < 4; ++mi)
            fa[mi] = *(const bf16x8*)(&Al[wm * 64 + mi * 16 + lr][lg * 8]);
        #pragma unroll
        for (int ni = 0; ni < 2; ++ni)
            fb[ni] = *(const bf16x8*)(&Bl[wn * 32 + ni * 16 + lr][lg * 8]);
        #pragma unroll
        for (int mi = 0; mi < 4; ++mi)
            #pragma unroll
            for (int ni = 0; ni < 2; ++ni)
                acc[mi][ni] = __builtin_amdgcn_mfma_f32_16x16x32_bf16(fa[mi], fb[ni], acc[mi][ni], 0, 0, 0);
        __syncthreads();
    }

    #pragma unroll
    for (int mi = 0; mi < 4; ++mi) {
        int rbase = m0 + wm * 64 + mi * 16 + lg * 4;
        #pragma unroll
        for (int v = 0; v < 4; ++v) {
            int gm = rbase + v;
            if (gm < M) {
                #pragma unroll
                for (int ni = 0; ni < 2; ++ni)
                    C[(size_t)gm * N + n0 + wn * 32 + ni * 16 + lr] = f2bf(acc[mi][ni][v]);
            }
        }
    }
}

// ---------------- gather aggregation (bf16 h), one wave per dst node, 4-deep MLP ----------------

__global__ __launch_bounds__(256) void k_agg256(const ushort* __restrict__ h,
                                                const int2* __restrict__ csr_p,
                                                const int* __restrict__ off,
                                                const int* __restrict__ deg,
                                                const float* __restrict__ dis,
                                                const float* __restrict__ bias,
                                                ushort* __restrict__ out, int n) {
    int wave = (int)((blockIdx.x * (size_t)blockDim.x + threadIdx.x) >> 6);
    int lane = threadIdx.x & 63;
    if (wave >= n) return;
    const int i = wave;
    const float di = dis[i];
    const int beg = off[i], cnt = deg[i] - 1, end = beg + cnt;

    float4 bv = ((const float4*)bias)[lane];
    ushort4 hv = ((const ushort4*)(h + (size_t)i * 256))[lane];
    float sl = di * di;
    float4 a0, a1 = {0,0,0,0}, a2 = {0,0,0,0}, a3 = {0,0,0,0};
    a0.x = fmaf(bf2f(hv.x), sl, bv.x);
    a0.y = fmaf(bf2f(hv.y), sl, bv.y);
    a0.z = fmaf(bf2f(hv.z), sl, bv.z);
    a0.w = fmaf(bf2f(hv.w), sl, bv.w);

    for (int base = beg; base < end; base += 64) {
        int m = end - base; if (m > 64) m = 64;
        int2 p = (lane < m) ? csr_p[base + lane] : make_int2(0, 0);
        int   msrc = p.x;
        float mw   = (lane < m) ? i2f(p.y) * di : 0.f;
        int k = 0;
        for (; k + 4 <= m; k += 4) {
            int s0 = __shfl(msrc, k),     s1 = __shfl(msrc, k + 1);
            int s2 = __shfl(msrc, k + 2), s3 = __shfl(msrc, k + 3);
            float w0 = __shfl(mw, k),     w1 = __shfl(mw, k + 1);
            float w2 = __shfl(mw, k + 2), w3 = __shfl(mw, k + 3);
            ushort4 v0 = ((const ushort4*)(h + (size_t)s0 * 256))[lane];
            ushort4 v1 = ((const ushort4*)(h + (size_t)s1 * 256))[lane];
            ushort4 v2 = ((const ushort4*)(h + (size_t)s2 * 256))[lane];
            ushort4 v3 = ((const ushort4*)(h + (size_t)s3 * 256))[lane];
            a0.x = fmaf(bf2f(v0.x), w0, a0.x); a0.y = fmaf(bf2f(v0.y), w0, a0.y);
            a0.z = fmaf(bf2f(v0.z), w0, a0.z); a0.w = fmaf(bf2f(v0.w), w0, a0.w);
            a1.x = fmaf(bf2f(v1.x), w1, a1.x); a1.y = fmaf(bf2f(v1.y), w1, a1.y);
            a1.z = fmaf(bf2f(v1.z), w1, a1.z); a1.w = fmaf(bf2f(v1.w), w1, a1.w);
            a2.x = fmaf(bf2f(v2.x), w2, a2.x); a2.y = fmaf(bf2f(v2.y), w2, a2.y);
            a2.z = fmaf(bf2f(v2.z), w2, a2.z); a2.w = fmaf(bf2f(v2.w), w2, a2.w);
            a3.x = fmaf(bf2f(v3.x), w3, a3.x); a3.y = fmaf(bf2f(v3.y), w3, a3.y);
            a3.z = fmaf(bf2f(v3.z), w3, a3.z); a3.w = fmaf(bf2f(v3.w), w3, a3.w);
        }
        for (; k < m; ++k) {
            int   s0 = __shfl(msrc, k); float w0 = __shfl(mw, k);
            ushort4 v0 = ((const ushort4*)(h + (size_t)s0 * 256))[lane];
            a0.x = fmaf(bf2f(v0.x), w0, a0.x); a0.y = fmaf(bf2f(v0.y), w0, a0.y);
            a0.z = fmaf(bf2f(v0.z), w0, a0.z); a0.w = fmaf(bf2f(v0.w), w0, a0.w);
        }
    }
    ushort4 o;
    o.x = f2bf((a0.x + a1.x) + (a2.x + a3.x));
    o.y = f2bf((a0.y + a1.y) + (a2.y + a3.y));
    o.z = f2bf((a0.z + a1.z) + (a2.z + a3.z));
    o.w = f2bf((a0.w + a1.w) + (a2.w + a3.w));
    ((ushort4*)(out + (size_t)i * 256))[lane] = o;
}

// agg64 fused with log-softmax: one wave per node; lane == class
__global__ __launch_bounds__(256) void k_agg64_lsm(const ushort* __restrict__ h,
                                                   const int2* __restrict__ csr_p,
                                                   const int* __restrict__ off,
                                                   const int* __restrict__ deg,
                                                   const float* __restrict__ dis,
                                                   const float* __restrict__ bias,
                                                   float* __restrict__ out, int n) {
    int wave = (int)((blockIdx.x * (size_t)blockDim.x + threadIdx.x) >> 6);
    int lane = threadIdx.x & 63;
    if (wave >= n) return;
    const int i = wave;
    const float di = dis[i];
    const int beg = off[i], cnt = deg[i] - 1, end = beg + cnt;

    float a0 = fmaf(bf2f(h[(size_t)i * 64 + lane]), di * di, bias[lane]);
    float a1 = 0.f, a2 = 0.f, a3 = 0.f;

    for (int base = beg; base < end; base += 64) {
        int m = end - base; if (m > 64) m = 64;
        int2 p = (lane < m) ? csr_p[base + lane] : make_int2(0, 0);
        int   msrc = p.x;
        float mw   = (lane < m) ? i2f(p.y) * di : 0.f;
        int k = 0;
        for (; k + 4 <= m; k += 4) {
            int s0 = __shfl(msrc, k),     s1 = __shfl(msrc, k + 1);
            int s2 = __shfl(msrc, k + 2), s3 = __shfl(msrc, k + 3);
            float w0 = __shfl(mw, k),     w1 = __shfl(mw, k + 1);
            float w2 = __shfl(mw, k + 2), w3 = __shfl(mw, k + 3);
            a0 = fmaf(bf2f(h[(size_t)s0 * 64 + lane]), w0, a0);
            a1 = fmaf(bf2f(h[(size_t)s1 * 64 + lane]), w1, a1);
            a2 = fmaf(bf2f(h[(size_t)s2 * 64 + lane]), w2, a2);
            a3 = fmaf(bf2f(h[(size_t)s3 * 64 + lane]), w3, a3);
        }
        for (; k < m; ++k) {
            int s0 = __shfl(msrc, k); float w0 = __shfl(mw, k);
            a0 = fmaf(bf2f(h[(size_t)s0 * 64 + lane]), w0, a0);
        }
    }
    float v = (a0 + a1) + (a2 + a3);

    float mx = v;
    #pragma unroll
    for (int o = 32; o > 0; o >>= 1) mx = fmaxf(mx, __shfl_xor(mx, o));
    float ex = __expf(v - mx);
    float ssum = ex;
    #pragma unroll
    for (int o = 32; o > 0; o >>= 1) ssum += __shfl_xor(ssum, o);
    out[(size_t)i * 64 + lane] = v - mx - logf(ssum);
}

// ---------------- launch ----------------

extern "C" void kernel_launch(void* const* d_in, const int* in_sizes, int n_in,
                              void* d_out, int out_size, void* d_ws, size_t ws_size,
                              hipStream_t stream) {
    const float* x  = (const float*)d_in[0];
    const int*   ei = (const int*)d_in[1];
    const float* W1 = (const float*)d_in[2];
    const float* b1 = (const float*)d_in[3];
    const float* W2 = (const float*)d_in[4];
    const float* b2 = (const float*)d_in[5];
    float* out = (float*)d_out;

    const int n = in_sizes[0] / 512;     // 100000
    const int E = in_sizes[1] / 2;       // 3200000
    const int* src = ei;
    const int* dst = ei + E;

    // workspace layout (bytes), 16B-aligned blocks
    char* ws = (char*)d_ws;
    int*    deg     = (int*)(ws + 0);               //    400,000
    int*    cursor  = (int*)(ws + 400000);          //    400,000
    float*  dis     = (float*)(ws + 800000);        //    400,000
    int*    offsets = (int*)(ws + 1200000);         //    400,000
    int*    partials= (int*)(ws + 1599488);         //        512 (scan block sums)
    int2*   csr_p   = (int2*)(ws + 1600000);        // 25,600,000 -> 27,200,000
    ushort* W1T     = (ushort*)(ws + 27200000);     //    262,144 -> 27,462,144
    ushort* W2T     = (ushort*)(ws + 27462144);     //     32,768 -> 27,494,912
    ushort* h1      = (ushort*)(ws + 27494912);     // 51,200,000 -> 78,694,912
    ushort* out1    = (ushort*)(ws + 78694912);     // 51,200,000 -> 129,894,912
    ushort* h2      = (ushort*)(ws + 129894912);    // 12,800,000 -> 142,694,912

    const int SB = (n + 1023) / 1024;   // scan blocks (98)

    // 0. weight transposes
    k_tcast<<<(512 * 256 + TB - 1) / TB, TB, 0, stream>>>(W1, W1T, 512, 256);
    k_tcast<<<(256 * 64 + TB - 1) / TB, TB, 0, stream>>>(W2, W2T, 256, 64);

    // 1. CSR build (hierarchical scan; packed {src, dis[src]}; cursor seeded with offsets)
    k_init_deg<<<(n + TB - 1) / TB, TB, 0, stream>>>(deg, n);
    k_count_deg<<<(E + TB - 1) / TB, TB, 0, stream>>>(dst, E, deg);
    k_dis<<<(n + TB - 1) / TB, TB, 0, stream>>>(deg, dis, n);
    k_scan_partial<<<SB, 256, 0, stream>>>(deg, partials, n);
    k_scan_tops<<<1, 128, 0, stream>>>(partials, SB);
    k_scan_final<<<SB, 256, 0, stream>>>(deg, partials, offsets, cursor, n);
    k_fill<<<(E + TB - 1) / TB, TB, 0, stream>>>(src, dst, E, cursor, dis, csr_p);

    // 2. h1 = x @ W1  (fp32 A converted in staging — no separate cast pass)
    {
        dim3 grid((n + 127) / 128, 256 / 64);
        k_gemm_mfma<true, false><<<grid, TB, 0, stream>>>(x, W1T, h1, n, 256, 512);
    }

    // 3. out1 = b1 + Â h1
    k_agg256<<<(n + 3) / 4, TB, 0, stream>>>(h1, csr_p, offsets, deg, dis, b1, out1, n);

    // 4. h2 = relu(out1) @ W2  (relu fused into A staging)
    {
        dim3 grid((n + 127) / 128, 1);
        k_gemm_mfma<false, true><<<grid, TB, 0, stream>>>(out1, W2T, h2, n, 64, 256);
    }

    // 5. out = b2 + Â h2, log-softmax fused (one pass, final write)
    k_agg64_lsm<<<(n + 3) / 4, TB, 0, stream>>>(h2, csr_p, offsets, deg, dis, b2, out, n);
}

// Round 8
// 725.780 us; speedup vs baseline: 1.3452x; 1.0477x over previous
//
#include <hip/hip_runtime.h>
#include <hip/hip_bf16.h>
#include <math.h>

#define TB 256

typedef __attribute__((ext_vector_type(8))) short bf16x8;
typedef __attribute__((ext_vector_type(4))) float f32x4;

__device__ inline float bf2f(ushort u) {
    union { uint u; float f; } c; c.u = ((uint)u) << 16; return c.f;
}
__device__ inline ushort f2bf(float f) {
    __hip_bfloat16 h = __float2bfloat16(f);
    union { __hip_bfloat16 h; ushort u; } c; c.h = h; return c.u;
}
__device__ inline float i2f(int i) { union { int i; float f; } c; c.i = i; return c.f; }
__device__ inline int f2i(float f) { union { float f; int i; } c; c.f = f; return c.i; }

// ---------------- weight transpose+cast: WT[n][k] = bf16(W[k][n]) ----------------

__global__ __launch_bounds__(256) void k_tcast(const float* __restrict__ W,
                                               ushort* __restrict__ WT, int K, int N) {
    int id = blockIdx.x * blockDim.x + threadIdx.x;
    if (id >= K * N) return;
    int k = id / N, nn = id % N;
    WT[(size_t)nn * K + k] = f2bf(W[id]);
}

// ---------------- degree ----------------

__global__ __launch_bounds__(256) void k_init_deg(int* deg, int n) {
    int i = blockIdx.x * blockDim.x + threadIdx.x;
    if (i < n) deg[i] = 1;
}

__global__ __launch_bounds__(256) void k_count_deg(const int* __restrict__ dst, int E, int* deg) {
    int i = blockIdx.x * blockDim.x + threadIdx.x;
    if (i < E) atomicAdd(&deg[dst[i]], 1);
}

// ---------------- hierarchical exclusive scan of (deg-1); also writes dis, cursor ----------------

__global__ __launch_bounds__(256) void k_scan_partial(const int* __restrict__ deg,
                                                      int* __restrict__ partials, int n) {
    __shared__ int red[256];
    int base = blockIdx.x * 1024;
    int t = threadIdx.x;
    int s = 0;
    #pragma unroll
    for (int j = 0; j < 4; ++j) {
        int i = base + t * 4 + j;
        if (i < n) s += deg[i] - 1;
    }
    red[t] = s;
    __syncthreads();
    for (int off = 128; off > 0; off >>= 1) {
        if (t < off) red[t] += red[t + off];
        __syncthreads();
    }
    if (t == 0) partials[blockIdx.x] = red[0];
}

__global__ __launch_bounds__(128) void k_scan_tops(int* __restrict__ partials, int B) {
    __shared__ int sh[128];
    int t = threadIdx.x;
    int v = (t < B) ? partials[t] : 0;
    sh[t] = v;
    __syncthreads();
    for (int off = 1; off < 128; off <<= 1) {
        int u = (t >= off) ? sh[t - off] : 0;
        __syncthreads();
        sh[t] += u;
        __syncthreads();
    }
    if (t < B) partials[t] = sh[t] - v;   // exclusive
}

__global__ __launch_bounds__(256) void k_scan_final(const int* __restrict__ deg,
                                                    const int* __restrict__ partials,
                                                    int* __restrict__ offsets,
                                                    int* __restrict__ cursor,
                                                    float* __restrict__ dis, int n) {
    __shared__ int sh[256];
    int base = blockIdx.x * 1024;
    int t = threadIdx.x;
    int c[4];
    int s = 0;
    #pragma unroll
    for (int j = 0; j < 4; ++j) {
        int i = base + t * 4 + j;
        c[j] = (i < n) ? deg[i] - 1 : 0;
        s += c[j];
    }
    sh[t] = s;
    __syncthreads();
    for (int off = 1; off < 256; off <<= 1) {
        int u = (t >= off) ? sh[t - off] : 0;
        __syncthreads();
        sh[t] += u;
        __syncthreads();
    }
    int run = partials[blockIdx.x] + sh[t] - s;
    #pragma unroll
    for (int j = 0; j < 4; ++j) {
        int i = base + t * 4 + j;
        if (i < n) {
            offsets[i] = run;
            cursor[i]  = run;
            dis[i] = rsqrtf((float)(c[j] + 1));
            run += c[j];
        }
    }
}

// ---------------- CSR fill (by dst): packed int2 {src, dis[src]} per edge ----------------

__global__ __launch_bounds__(256) void k_fill(const int* __restrict__ src, const int* __restrict__ dst, int E,
                                              int* cursor,
                                              const float* __restrict__ dis,
                                              int2* __restrict__ csr_p) {
    int e = blockIdx.x * blockDim.x + threadIdx.x;
    if (e >= E) return;
    int d = dst[e];
    int s = src[e];
    int pos = atomicAdd(&cursor[d], 1);
    csr_p[pos] = make_int2(s, f2i(dis[s]));
}

// ---------------- GEMM1: C[M,256] = bf16(A_fp32[M,512]) @ W1T[256,512]^T ----------------
// BM=64, BN=256 (full width -> A read exactly once), BK=32, 4 waves, each 64 rows x 64 cols.

__global__ __launch_bounds__(256) void k_gemm1(const float* __restrict__ A,
                                               const ushort* __restrict__ BT,
                                               ushort* __restrict__ C,
                                               int M, int N, int K) {
    const int BM = 64, BN = 256, BK = 32;
    __shared__ ushort Al[BM][40];
    __shared__ ushort Bl[BN][40];

    const int t    = threadIdx.x;
    const int lane = t & 63;
    const int wid  = t >> 6;          // column slice 0..3
    const int m0   = blockIdx.x * BM;
    const int lr   = lane & 15;
    const int lg   = lane >> 4;

    f32x4 acc[4][4] = {};

    for (int k0 = 0; k0 < K; k0 += BK) {
        // stage A: 64 rows x 32 fp32 -> bf16 ; thread t: row t>>2, quarter t&3 (8 elems)
        {
            int row = t >> 2, q = t & 3;
            int gm = m0 + row;
            ushort4 o0 = {0,0,0,0}, o1 = {0,0,0,0};
            if (gm < M) {
                const float* ap = A + (size_t)gm * K + k0 + q * 8;
                float4 u = *(const float4*)ap;
                float4 w = *(const float4*)(ap + 4);
                o0.x = f2bf(u.x); o0.y = f2bf(u.y); o0.z = f2bf(u.z); o0.w = f2bf(u.w);
                o1.x = f2bf(w.x); o1.y = f2bf(w.y); o1.z = f2bf(w.z); o1.w = f2bf(w.w);
            }
            *(ushort4*)(&Al[row][q * 8])     = o0;
            *(ushort4*)(&Al[row][q * 8 + 4]) = o1;
        }
        // stage B: 256 rows x 32 bf16; thread t handles row t (64 B, L2-resident)
        {
            const ushort* bp = BT + (size_t)t * K + k0;
            uint4 v0 = *(const uint4*)bp;
            uint4 v1 = *(const uint4*)(bp + 8);
            uint4 v2 = *(const uint4*)(bp + 16);
            uint4 v3 = *(const uint4*)(bp + 24);
            *(uint4*)(&Bl[t][0])  = v0;
            *(uint4*)(&Bl[t][8])  = v1;
            *(uint4*)(&Bl[t][16]) = v2;
            *(uint4*)(&Bl[t][24]) = v3;
        }
        __syncthreads();

        bf16x8 fa[4], fb[4];
        #pragma unroll
        for (int mi = 0; mi < 4; ++mi)
            fa[mi] = *(const bf16x8*)(&Al[mi * 16 + lr][lg * 8]);
        #pragma unroll
        for (int ni = 0; ni < 4; ++ni)
            fb[ni] = *(const bf16x8*)(&Bl[wid * 64 + ni * 16 + lr][lg * 8]);
        #pragma unroll
        for (int mi = 0; mi < 4; ++mi)
            #pragma unroll
            for (int ni = 0; ni < 4; ++ni)
                acc[mi][ni] = __builtin_amdgcn_mfma_f32_16x16x32_bf16(fa[mi], fb[ni], acc[mi][ni], 0, 0, 0);
        __syncthreads();
    }

    #pragma unroll
    for (int mi = 0; mi < 4; ++mi) {
        int rbase = m0 + mi * 16 + lg * 4;
        #pragma unroll
        for (int v = 0; v < 4; ++v) {
            int gm = rbase + v;
            if (gm < M) {
                #pragma unroll
                for (int ni = 0; ni < 4; ++ni)
                    C[(size_t)gm * N + wid * 64 + ni * 16 + lr] = f2bf(acc[mi][ni][v]);
            }
        }
    }
}

// ---------------- GEMM2: C[M,64] = relu(A_bf16[M,256]) @ W2T[64,256]^T ----------------
// BM=128, BN=64 (full width), BK=32; 4 waves (2x2).

__device__ inline uint relu_pk(uint u) {
    uint lo = u & 0x0000FFFFu;
    uint hi = u & 0xFFFF0000u;
    if (u & 0x00008000u) lo = 0;
    if (u & 0x80000000u) hi = 0;
    return lo | hi;
}

__global__ __launch_bounds__(256) void k_gemm2(const ushort* __restrict__ A,
                                               const ushort* __restrict__ BT,
                                               ushort* __restrict__ C,
                                               int M, int N, int K) {
    const int BM = 128, BN = 64, BK = 32;
    __shared__ ushort Al[BM][40];
    __shared__ ushort Bl[BN][40];

    const int t    = threadIdx.x;
    const int lane = t & 63;
    const int wid  = t >> 6;
    const int wm   = wid >> 1, wn = wid & 1;
    const int m0   = blockIdx.x * BM;
    const int lr   = lane & 15;
    const int lg   = lane >> 4;

    f32x4 acc[4][2] = {};

    for (int k0 = 0; k0 < K; k0 += BK) {
        #pragma unroll
        for (int i = 0; i < 2; ++i) {
            int c = t + i * 256;
            int row = c >> 2, q = c & 3;
            int gm = m0 + row;
            uint4 v = make_uint4(0, 0, 0, 0);
            if (gm < M) v = *(const uint4*)(A + (size_t)gm * K + k0 + q * 8);
            v.x = relu_pk(v.x); v.y = relu_pk(v.y); v.z = relu_pk(v.z); v.w = relu_pk(v.w);
            *(uint4*)(&Al[row][q * 8]) = v;
        }
        {
            int row = t >> 2, q = t & 3;
            uint4 v = *(const uint4*)(BT + (size_t)(row) * K + k0 + q * 8);
            *(uint4*)(&Bl[row][q * 8]) = v;
        }
        __syncthreads();

        bf16x8 fa[4], fb[2];
        #pragma unroll
        for (int mi = 0; mi < 4; ++mi)
            fa[mi] = *(const bf16x8*)(&Al[wm * 64 + mi * 16 + lr][lg * 8]);
        #pragma unroll
        for (int ni = 0; ni < 2; ++ni)
            fb[ni] = *(const bf16x8*)(&Bl[wn * 32 + ni * 16 + lr][lg * 8]);
        #pragma unroll
        for (int mi = 0; mi < 4; ++mi)
            #pragma unroll
            for (int ni = 0; ni < 2; ++ni)
                acc[mi][ni] = __builtin_amdgcn_mfma_f32_16x16x32_bf16(fa[mi], fb[ni], acc[mi][ni], 0, 0, 0);
        __syncthreads();
    }

    #pragma unroll
    for (int mi = 0; mi < 4; ++mi) {
        int rbase = m0 + wm * 64 + mi * 16 + lg * 4;
        #pragma unroll
        for (int v = 0; v < 4; ++v) {
            int gm = rbase + v;
            if (gm < M) {
                #pragma unroll
                for (int ni = 0; ni < 2; ++ni)
                    C[(size_t)gm * N + wn * 32 + ni * 16 + lr] = f2bf(acc[mi][ni][v]);
            }
        }
    }
}

// ---------------- gather aggregation, feature-half pass (128 feats, ushort2/lane) ----------------

__global__ __launch_bounds__(256) void k_agg256h(const ushort* __restrict__ h,
                                                 const int2* __restrict__ csr_p,
                                                 const int* __restrict__ off,
                                                 const int* __restrict__ deg,
                                                 const float* __restrict__ dis,
                                                 const float* __restrict__ bias,
                                                 ushort* __restrict__ out, int n, int foff) {
    int wave = (int)((blockIdx.x * (size_t)blockDim.x + threadIdx.x) >> 6);
    int lane = threadIdx.x & 63;
    if (wave >= n) return;
    const int i = wave;
    const float di = dis[i];
    const int beg = off[i], cnt = deg[i] - 1, end = beg + cnt;

    float2 bv = ((const float2*)(bias + foff))[lane];
    ushort2 hv = ((const ushort2*)(h + (size_t)i * 256 + foff))[lane];
    float sl = di * di;
    float2 a0, a1 = {0,0}, a2 = {0,0}, a3 = {0,0};
    a0.x = fmaf(bf2f(hv.x), sl, bv.x);
    a0.y = fmaf(bf2f(hv.y), sl, bv.y);

    for (int base = beg; base < end; base += 64) {
        int m = end - base; if (m > 64) m = 64;
        int2 p = (lane < m) ? csr_p[base + lane] : make_int2(0, 0);
        int   msrc = p.x;
        float mw   = (lane < m) ? i2f(p.y) * di : 0.f;
        int k = 0;
        for (; k + 4 <= m; k += 4) {
            int s0 = __shfl(msrc, k),     s1 = __shfl(msrc, k + 1);
            int s2 = __shfl(msrc, k + 2), s3 = __shfl(msrc, k + 3);
            float w0 = __shfl(mw, k),     w1 = __shfl(mw, k + 1);
            float w2 = __shfl(mw, k + 2), w3 = __shfl(mw, k + 3);
            ushort2 v0 = ((const ushort2*)(h + (size_t)s0 * 256 + foff))[lane];
            ushort2 v1 = ((const ushort2*)(h + (size_t)s1 * 256 + foff))[lane];
            ushort2 v2 = ((const ushort2*)(h + (size_t)s2 * 256 + foff))[lane];
            ushort2 v3 = ((const ushort2*)(h + (size_t)s3 * 256 + foff))[lane];
            a0.x = fmaf(bf2f(v0.x), w0, a0.x); a0.y = fmaf(bf2f(v0.y), w0, a0.y);
            a1.x = fmaf(bf2f(v1.x), w1, a1.x); a1.y = fmaf(bf2f(v1.y), w1, a1.y);
            a2.x = fmaf(bf2f(v2.x), w2, a2.x); a2.y = fmaf(bf2f(v2.y), w2, a2.y);
            a3.x = fmaf(bf2f(v3.x), w3, a3.x); a3.y = fmaf(bf2f(v3.y), w3, a3.y);
        }
        for (; k < m; ++k) {
            int   s0 = __shfl(msrc, k); float w0 = __shfl(mw, k);
            ushort2 v0 = ((const ushort2*)(h + (size_t)s0 * 256 + foff))[lane];
            a0.x = fmaf(bf2f(v0.x), w0, a0.x); a0.y = fmaf(bf2f(v0.y), w0, a0.y);
        }
    }
    ushort2 o;
    o.x = f2bf((a0.x + a1.x) + (a2.x + a3.x));
    o.y = f2bf((a0.y + a1.y) + (a2.y + a3.y));
    ((ushort2*)(out + (size_t)i * 256 + foff))[lane] = o;
}

// ---------------- agg64 fused with log-softmax: one wave per node; lane == class ----------------

__global__ __launch_bounds__(256) void k_agg64_lsm(const ushort* __restrict__ h,
                                                   const int2* __restrict__ csr_p,
                                                   const int* __restrict__ off,
                                                   const int* __restrict__ deg,
                                                   const float* __restrict__ dis,
                                                   const float* __restrict__ bias,
                                                   float* __restrict__ out, int n) {
    int wave = (int)((blockIdx.x * (size_t)blockDim.x + threadIdx.x) >> 6);
    int lane = threadIdx.x & 63;
    if (wave >= n) return;
    const int i = wave;
    const float di = dis[i];
    const int beg = off[i], cnt = deg[i] - 1, end = beg + cnt;

    float a0 = fmaf(bf2f(h[(size_t)i * 64 + lane]), di * di, bias[lane]);
    float a1 = 0.f, a2 = 0.f, a3 = 0.f;

    for (int base = beg; base < end; base += 64) {
        int m = end - base; if (m > 64) m = 64;
        int2 p = (lane < m) ? csr_p[base + lane] : make_int2(0, 0);
        int   msrc = p.x;
        float mw   = (lane < m) ? i2f(p.y) * di : 0.f;
        int k = 0;
        for (; k + 4 <= m; k += 4) {
            int s0 = __shfl(msrc, k),     s1 = __shfl(msrc, k + 1);
            int s2 = __shfl(msrc, k + 2), s3 = __shfl(msrc, k + 3);
            float w0 = __shfl(mw, k),     w1 = __shfl(mw, k + 1);
            float w2 = __shfl(mw, k + 2), w3 = __shfl(mw, k + 3);
            a0 = fmaf(bf2f(h[(size_t)s0 * 64 + lane]), w0, a0);
            a1 = fmaf(bf2f(h[(size_t)s1 * 64 + lane]), w1, a1);
            a2 = fmaf(bf2f(h[(size_t)s2 * 64 + lane]), w2, a2);
            a3 = fmaf(bf2f(h[(size_t)s3 * 64 + lane]), w3, a3);
        }
        for (; k < m; ++k) {
            int s0 = __shfl(msrc, k); float w0 = __shfl(mw, k);
            a0 = fmaf(bf2f(h[(size_t)s0 * 64 + lane]), w0, a0);
        }
    }
    float v = (a0 + a1) + (a2 + a3);

    float mx = v;
    #pragma unroll
    for (int o = 32; o > 0; o >>= 1) mx = fmaxf(mx, __shfl_xor(mx, o));
    float ex = __expf(v - mx);
    float ssum = ex;
    #pragma unroll
    for (int o = 32; o > 0; o >>= 1) ssum += __shfl_xor(ssum, o);
    out[(size_t)i * 64 + lane] = v - mx - logf(ssum);
}

// ---------------- launch ----------------

extern "C" void kernel_launch(void* const* d_in, const int* in_sizes, int n_in,
                              void* d_out, int out_size, void* d_ws, size_t ws_size,
                              hipStream_t stream) {
    const float* x  = (const float*)d_in[0];
    const int*   ei = (const int*)d_in[1];
    const float* W1 = (const float*)d_in[2];
    const float* b1 = (const float*)d_in[3];
    const float* W2 = (const float*)d_in[4];
    const float* b2 = (const float*)d_in[5];
    float* out = (float*)d_out;

    const int n = in_sizes[0] / 512;     // 100000
    const int E = in_sizes[1] / 2;       // 3200000
    const int* src = ei;
    const int* dst = ei + E;

    // workspace layout (bytes), 16B-aligned blocks
    char* ws = (char*)d_ws;
    int*    deg     = (int*)(ws + 0);               //    400,000
    int*    cursor  = (int*)(ws + 400000);          //    400,000
    float*  dis     = (float*)(ws + 800000);        //    400,000
    int*    offsets = (int*)(ws + 1200000);         //    400,000
    int*    partials= (int*)(ws + 1599488);         //        512
    int2*   csr_p   = (int2*)(ws + 1600000);        // 25,600,000 -> 27,200,000
    ushort* W1T     = (ushort*)(ws + 27200000);     //    262,144 -> 27,462,144
    ushort* W2T     = (ushort*)(ws + 27462144);     //     32,768 -> 27,494,912
    ushort* h1      = (ushort*)(ws + 27494912);     // 51,200,000 -> 78,694,912
    ushort* out1    = (ushort*)(ws + 78694912);     // 51,200,000 -> 129,894,912
    ushort* h2      = (ushort*)(ws + 129894912);    // 12,800,000 -> 142,694,912

    const int SB = (n + 1023) / 1024;   // scan blocks

    // 0. weight transposes
    k_tcast<<<(512 * 256 + TB - 1) / TB, TB, 0, stream>>>(W1, W1T, 512, 256);
    k_tcast<<<(256 * 64 + TB - 1) / TB, TB, 0, stream>>>(W2, W2T, 256, 64);

    // 1. CSR build
    k_init_deg<<<(n + TB - 1) / TB, TB, 0, stream>>>(deg, n);
    k_count_deg<<<(E + TB - 1) / TB, TB, 0, stream>>>(dst, E, deg);
    k_scan_partial<<<SB, 256, 0, stream>>>(deg, partials, n);
    k_scan_tops<<<1, 128, 0, stream>>>(partials, SB);
    k_scan_final<<<SB, 256, 0, stream>>>(deg, partials, offsets, cursor, dis, n);
    k_fill<<<(E + TB - 1) / TB, TB, 0, stream>>>(src, dst, E, cursor, dis, csr_p);

    // 2. h1 = x @ W1  (full-width tile: A read exactly once)
    k_gemm1<<<(n + 63) / 64, TB, 0, stream>>>(x, W1T, h1, n, 256, 512);

    // 3. out1 = b1 + Â h1  (two feature-half passes for L2 footprint)
    k_agg256h<<<(n + 3) / 4, TB, 0, stream>>>(h1, csr_p, offsets, deg, dis, b1, out1, n, 0);
    k_agg256h<<<(n + 3) / 4, TB, 0, stream>>>(h1, csr_p, offsets, deg, dis, b1, out1, n, 128);

    // 4. h2 = relu(out1) @ W2
    k_gemm2<<<(n + 127) / 128, TB, 0, stream>>>(out1, W2T, h2, n, 64, 256);

    // 5. out = b2 + Â h2, log-softmax fused
    k_agg64_lsm<<<(n + 3) / 4, TB, 0, stream>>>(h2, csr_p, offsets, deg, dis, b2, out, n);
}